// Round 6
// baseline (242.218 us; speedup 1.0000x reference)
//
#include <hip/hip_runtime.h>

// GaussianActionField: out[b][k][y] = sum_n exp(-(x[b]·P[n,:,k] - pos[n]·P[n,:,k])^2 / (2 sigma[n,k]^2)) * color[n][y]
// B=256 N=65536 XD=32 YD=64 K=8. sigma=0.01 -> ~1.6% of (b,n,k) pass the exp cutoff g>2^-40.
// gaf_screen: EXACT x·P via 3-way bf16 split (x=X0+X1+X2, P=P0+P1+P2) and 6 MFMAs per
//   tile (terms i+j<=2, abs err ~1e-5 -- same class as fp32). Passing C-elements go
//   straight to per-(b,k) buckets (predicated lane atomic). No worklist, no recompute.
// gaf_phase2: one 4-wave block per (b,k) bucket reduces g*color into out.

typedef __attribute__((ext_vector_type(8))) short short8;
typedef __attribute__((ext_vector_type(4))) float f32x4;

#define NTOT   65536
#define XD     32
#define YD     64
#define KK     8
#define BB     256
#define CN     16        // n's per chunk/block
#define NKC    (CN*KK)   // 128 nk columns per chunk
#define TPB1   256       // 4 waves; 31.7KB LDS -> 4-5 blocks/CU
#define PBS    40        // sPb stride (bf16 elems): 80B rows
#define NTILES (BB*KK)

__device__ __forceinline__ unsigned short f2bf(float f) {   // fp32 -> bf16 RNE
  unsigned u = __float_as_uint(f);
  u += 0x7FFFu + ((u >> 16) & 1u);
  return (unsigned short)(u >> 16);
}
__device__ __forceinline__ float bf2f(unsigned short h) {
  return __uint_as_float((unsigned)h << 16);
}
__device__ __forceinline__ void split3(float v, unsigned short& h0,
                                       unsigned short& h1, unsigned short& h2) {
  h0 = f2bf(v);
  float r1 = v - bf2f(h0);
  h1 = f2bf(r1);
  float r2 = r1 - bf2f(h1);
  h2 = f2bf(r2);
}

__global__ __launch_bounds__(TPB1, 4)
void gaf_screen(const float* __restrict__ x, const float* __restrict__ pos,
                const float* __restrict__ proj, const float* __restrict__ sig,
                unsigned* __restrict__ cnt, int2* __restrict__ ent, int cap) {
  __shared__ unsigned short sPb0[NKC][PBS];    // P split-0 bf16 [nk][i]  10240B
  __shared__ unsigned short sPb1[NKC][PBS];    // P split-1               10240B
  __shared__ unsigned short sPb2[NKC][PBS];    // P split-2               10240B
  __shared__ float2         sMeta[NKC];        // (posP, -log2e/(2 s^2))   1024B

  const int t  = threadIdx.x;
  const int n0 = blockIdx.x * CN;

  // ---- stage P chunk as 3-way bf16 split (1024 float4, coalesced) ----
  {
    const float4* Pg = (const float4*)(proj + (size_t)n0 * XD * KK);
#pragma unroll
    for (int r = 0; r < 4; ++r) {
      int f = t + r * TPB1;
      float4 v = Pg[f];
      int nn = f >> 6;                 // 64 float4 per n
      int i  = (f & 63) >> 1;          // 2 float4 per i
      int nk = nn * KK + ((f & 1) << 2);
      split3(v.x, sPb0[nk+0][i], sPb1[nk+0][i], sPb2[nk+0][i]);
      split3(v.y, sPb0[nk+1][i], sPb1[nk+1][i], sPb2[nk+1][i]);
      split3(v.z, sPb0[nk+2][i], sPb1[nk+2][i], sPb2[nk+2][i]);
      split3(v.w, sPb0[nk+3][i], sPb1[nk+3][i], sPb2[nk+3][i]);
    }
  }

  // ---- exact fp32 posP (pos + P gathered from global, L2-hot), exponent scale ----
  if (t < NKC) {
    int nn = t >> 3, k = t & 7;
    const float4* pg = (const float4*)(pos + (size_t)(n0 + nn) * XD);
    const float*  pk = proj + (size_t)(n0 + nn) * XD * KK + k;   // stride-8 column
    float d = 0.f;
#pragma unroll
    for (int j = 0; j < 8; ++j) {
      float4 v = pg[j];
      d = fmaf(v.x, pk[(4*j+0) * KK], d);
      d = fmaf(v.y, pk[(4*j+1) * KK], d);
      d = fmaf(v.z, pk[(4*j+2) * KK], d);
      d = fmaf(v.w, pk[(4*j+3) * KK], d);
    }
    float s = sig[(size_t)n0 * KK + t];
    sMeta[t] = make_float2(d, -0.72134752044448169f / (s * s));
  }

  // ---- A fragments: x rows split 3-way; wave w + sub-tile j -> b-tile j*4+w ----
  const int l  = t & 63, w = t >> 6;
  const int i0 = (l >> 4) << 3;                // this lane's k-slice
  short8 af0[4], af1[4], af2[4];
#pragma unroll
  for (int j = 0; j < 4; ++j) {
    const int brow = (j * 4 + w) * 16 + (l & 15);
    const float4* xr = (const float4*)(x + (size_t)brow * XD + i0);
    float4 u0 = xr[0], u1 = xr[1];
    unsigned short h0, h1, h2;
    split3(u0.x, h0, h1, h2); af0[j][0]=(short)h0; af1[j][0]=(short)h1; af2[j][0]=(short)h2;
    split3(u0.y, h0, h1, h2); af0[j][1]=(short)h0; af1[j][1]=(short)h1; af2[j][1]=(short)h2;
    split3(u0.z, h0, h1, h2); af0[j][2]=(short)h0; af1[j][2]=(short)h1; af2[j][2]=(short)h2;
    split3(u0.w, h0, h1, h2); af0[j][3]=(short)h0; af1[j][3]=(short)h1; af2[j][3]=(short)h2;
    split3(u1.x, h0, h1, h2); af0[j][4]=(short)h0; af1[j][4]=(short)h1; af2[j][4]=(short)h2;
    split3(u1.y, h0, h1, h2); af0[j][5]=(short)h0; af1[j][5]=(short)h1; af2[j][5]=(short)h2;
    split3(u1.z, h0, h1, h2); af0[j][6]=(short)h0; af1[j][6]=(short)h1; af2[j][6]=(short)h2;
    split3(u1.w, h0, h1, h2); af0[j][7]=(short)h0; af1[j][7]=(short)h1; af2[j][7]=(short)h2;
  }
  __syncthreads();

  // ---- exact-split MFMA screen + direct bucket append ----
  const f32x4 zero = {0.f, 0.f, 0.f, 0.f};
#pragma unroll
  for (int nkt = 0; nkt < NKC / 16; ++nkt) {
    const int col = nkt * 16 + (l & 15);
    short8 b0 = *(const short8*)&sPb0[col][i0];
    short8 b1 = *(const short8*)&sPb1[col][i0];
    short8 b2 = *(const short8*)&sPb2[col][i0];
    float2 mt = sMeta[col];
#pragma unroll
    for (int j = 0; j < 4; ++j) {
      // small terms first, a0*b0 last (fp32 C-accumulation)
      f32x4 S = __builtin_amdgcn_mfma_f32_16x16x32_bf16(af2[j], b0, zero, 0, 0, 0);
      S = __builtin_amdgcn_mfma_f32_16x16x32_bf16(af0[j], b2, S, 0, 0, 0);
      S = __builtin_amdgcn_mfma_f32_16x16x32_bf16(af1[j], b1, S, 0, 0, 0);
      S = __builtin_amdgcn_mfma_f32_16x16x32_bf16(af1[j], b0, S, 0, 0, 0);
      S = __builtin_amdgcn_mfma_f32_16x16x32_bf16(af0[j], b1, S, 0, 0, 0);
      S = __builtin_amdgcn_mfma_f32_16x16x32_bf16(af0[j], b0, S, 0, 0, 0);
#pragma unroll
      for (int r = 0; r < 4; ++r) {
        float d  = S[r] - mt.x;
        float t0 = d * d * mt.y;
        if (t0 > -40.f) {                        // g >= 2^-40
          int b  = (j * 4 + w) * 16 + ((l >> 4) << 2) + r;  // C/D: row=(l>>4)*4+r
          int bk = b * KK + (col & 7);
          unsigned idx = atomicAdd(&cnt[bk], 1u);
          if (idx < (unsigned)cap)
            ent[(size_t)bk * cap + idx] =
                make_int2(n0 + (col >> 3), __float_as_int(__builtin_amdgcn_exp2f(t0)));
        }
      }
    }
  }
}

__global__ __launch_bounds__(256, 8)
void gaf_phase2(const unsigned* __restrict__ cnt,
                const int2* __restrict__ ent,
                const float* __restrict__ colr,
                float* __restrict__ out,
                int cap) {
  __shared__ float sPart[4][YD];
  const int t = threadIdx.x;
  const int w = t >> 6, lane = t & 63;
  const int tile = blockIdx.x;
  int m = (int)cnt[tile];
  if (m > cap) m = cap;
  const int2* e = ent + (size_t)tile * cap;

  float a0 = 0.f, a1 = 0.f, a2 = 0.f, a3 = 0.f,
        a4 = 0.f, a5 = 0.f, a6 = 0.f, a7 = 0.f;
  int i = w;
  for (; i + 28 < m; i += 32) {                  // wave w: entries w, w+4, ..., w+28
    int2 e0 = e[i+0],  e1 = e[i+4],  e2 = e[i+8],  e3 = e[i+12];
    int2 e4 = e[i+16], e5 = e[i+20], e6 = e[i+24], e7 = e[i+28];
    a0 = fmaf(__int_as_float(e0.y), colr[(size_t)e0.x * YD + lane], a0);
    a1 = fmaf(__int_as_float(e1.y), colr[(size_t)e1.x * YD + lane], a1);
    a2 = fmaf(__int_as_float(e2.y), colr[(size_t)e2.x * YD + lane], a2);
    a3 = fmaf(__int_as_float(e3.y), colr[(size_t)e3.x * YD + lane], a3);
    a4 = fmaf(__int_as_float(e4.y), colr[(size_t)e4.x * YD + lane], a4);
    a5 = fmaf(__int_as_float(e5.y), colr[(size_t)e5.x * YD + lane], a5);
    a6 = fmaf(__int_as_float(e6.y), colr[(size_t)e6.x * YD + lane], a6);
    a7 = fmaf(__int_as_float(e7.y), colr[(size_t)e7.x * YD + lane], a7);
  }
  for (; i < m; i += 4) {
    int2 q = e[i];
    a0 = fmaf(__int_as_float(q.y), colr[(size_t)q.x * YD + lane], a0);
  }
  sPart[w][lane] = ((a0 + a1) + (a2 + a3)) + ((a4 + a5) + (a6 + a7));
  __syncthreads();
  if (w == 0)
    out[(size_t)tile * YD + lane] =
        (sPart[0][lane] + sPart[1][lane]) + (sPart[2][lane] + sPart[3][lane]);
}

extern "C" void kernel_launch(void* const* d_in, const int* in_sizes, int n_in,
                              void* d_out, int out_size, void* d_ws, size_t ws_size,
                              hipStream_t stream) {
  const float* x    = (const float*)d_in[0];
  const float* pos  = (const float*)d_in[1];
  const float* proj = (const float*)d_in[2];
  const float* colr = (const float*)d_in[3];
  const float* sig  = (const float*)d_in[4];
  float* out = (float*)d_out;

  unsigned* cnt = (unsigned*)d_ws;
  int2* ent = (int2*)((char*)d_ws + 8192);
  size_t avail = (ws_size > 8192) ? (ws_size - 8192) / (sizeof(int2) * NTILES) : 0;
  int cap = (int)(avail < 1024 ? avail : 1024);

  hipMemsetAsync(d_ws, 0, 8192, stream);         // zero bucket counters

  gaf_screen<<<NTOT / CN, TPB1, 0, stream>>>(x, pos, proj, sig, cnt, ent, cap);
  gaf_phase2<<<NTILES, 256, 0, stream>>>(cnt, ent, colr, out, cap);
}